// Round 1
// 56.572 us; speedup vs baseline: 1.0801x; 1.0801x over previous
//
#include <hip/hip_runtime.h>

// QConv1D quantum-circuit conv, analytically reduced to 64 monomials.
//
// exp_val(oc,p) = sum_{s=0..63} T[oc][s] * M_p[s],
//   M_p[s] = prod_q u_q(s),  u_q = odd ? (in ? sin x_q : 1) : cos x_q
//   (in = q in S; odd = parity of ring-neighbors of q in S)
// T[oc][s] = sign * prod_q f_q,  f = in ? (odd ? -s2 : -s2*c1)
//                                       : (odd ?  c2 : -c2*s1),
//   sign = (-1)^{E_SS} * (-1)^{n1/2}   (validated in R1, absmax 2e-3).
//
// R3: latency-bound fix. Old shape: 128 blocks (half the CUs idle, 1
// wave/SIMD, 128 dependent ds_reads/thread, 16x-scattered stores).
// New shape: s-loop split 4-ways across WAVES (squad = wave id, kept
// wave-uniform so the monomial bit logic still constant-folds via a
// uniform switch over 4 fully-unrolled 16-s bodies):
//   thread = (c, half, squad): 512 blocks x 256 thr = 8 waves/CU.
//   block = (r0, c0..c0+32) output slab -> epilogue stores are 128B
//   contiguous runs (was: every lane store on its own cacheline).
// Cross-squad reduce via 8KB LDS (all LDS patterns <=2-way = free).
//
// Output scramble (reference reshape quirk, Bn==OUT_CH==16, L_out*OUT_CH==Np):
//   out[oc*16352 + r*1022 + c] = exp_val(oc, p),  p = c*16 + r.

#define L_IN  1024
#define L_OUT 1022
#define NP    16352   // 16 * 1022
#define NS    64

// One 16-s chunk, S0 compile-time so (s>>q)&1 etc. fold and the T-row
// offsets are immediates. Tsrc already includes the half*8 offset.
template<int S0>
__device__ __forceinline__ void s_chunk(const float* __restrict__ Tsrc,
                                        const float* cx, const float* sx,
                                        float acc[8])
{
    #pragma unroll
    for (int s = S0; s < S0 + 16; ++s) {
        float m = 1.f;
        #pragma unroll
        for (int q = 0; q < 6; ++q) {
            const int in  = (s >> q) & 1;
            const int odd = (((s >> ((q + 1) % 6)) ^ (s >> ((q + 5) % 6)))) & 1;
            if (odd) { if (in) m *= sx[q]; }
            else       m *= cx[q];
        }
        const float4 t0 = *(const float4*)(Tsrc + s * 16);
        const float4 t1 = *(const float4*)(Tsrc + s * 16 + 4);
        acc[0] = fmaf(t0.x, m, acc[0]);
        acc[1] = fmaf(t0.y, m, acc[1]);
        acc[2] = fmaf(t0.z, m, acc[2]);
        acc[3] = fmaf(t0.w, m, acc[3]);
        acc[4] = fmaf(t1.x, m, acc[4]);
        acc[5] = fmaf(t1.y, m, acc[5]);
        acc[6] = fmaf(t1.z, m, acc[6]);
        acc[7] = fmaf(t1.w, m, acc[7]);
    }
}

__global__ __launch_bounds__(256, 2) void qconv_kernel(
    const float* __restrict__ x, const float* __restrict__ w,
    float* __restrict__ out)
{
    __shared__ float T[NS * 16];            // T[s*16 + oc], 4KB
    __shared__ float part[8][4][2][32];     // [j][squad][half][cidx], 8KB

    const int tid = threadIdx.x;

    // ---- build T: thread -> oc = tid&15 (fixed), s = (tid>>4) + 16k ----
    {
        const int oc = tid & 15;
        const float4* wv = (const float4*)(w + oc * 12);  // 48B rows, aligned
        const float4 w0 = wv[0], w1 = wv[1], w2 = wv[2];
        const float th1[6] = {w0.x, w0.z, w1.x, w1.z, w2.x, w2.z};
        const float th2[6] = {w0.y, w0.w, w1.y, w1.w, w2.y, w2.w};
        float v00[6], v01[6], v10[6], v11[6];   // f by (in,odd), per q
        #pragma unroll
        for (int q = 0; q < 6; ++q) {
            float s1, c1, s2, c2;
            __sincosf(th1[q], &s1, &c1);
            __sincosf(th2[q], &s2, &c2);
            v00[q] = -c2 * s1;   // in=0, odd=0
            v01[q] =  c2;        // in=0, odd=1
            v10[q] = -s2 * c1;   // in=1, odd=0
            v11[q] = -s2;        // in=1, odd=1
        }
        const int sb = tid >> 4;
        #pragma unroll
        for (int k = 0; k < 4; ++k) {
            const int s = sb + 16 * k;
            float prod = 1.f;
            int ess = 0, n1 = 0;
            #pragma unroll
            for (int q = 0; q < 6; ++q) {
                const int in  = (s >> q) & 1;
                const int nxt = (s >> ((q + 1) % 6)) & 1;
                const int prv = (s >> ((q + 5) % 6)) & 1;
                const int odd = (nxt + prv) & 1;
                const float f = in ? (odd ? v11[q] : v10[q])
                                   : (odd ? v01[q] : v00[q]);
                ess += in & nxt;
                n1  += in & odd;
                prod *= f;
            }
            if ((ess ^ (n1 >> 1)) & 1) prod = -prod;
            T[s * 16 + oc] = prod;   // banks 2-way max: free
        }
    }
    __syncthreads();

    // ---- mapping: block = (r0, 32-wide c chunk); wave = squad ----
    const int bid   = blockIdx.x;
    const int r0    = bid & 15;
    const int c0    = (bid >> 4) << 5;
    const int squad = tid >> 6;              // wave-uniform s-chunk id
    const int lane  = tid & 63;
    const int half  = lane >> 5;             // oc half
    const int cidx  = lane & 31;
    const int c     = c0 + cidx;
    const int cc    = (c < L_OUT) ? c : (L_OUT - 1);   // clamp tail lanes
    const int p     = cc * 16 + r0;
    const int bi    = p / L_OUT;
    const int li    = p - bi * L_OUT;

    const float* xb = x + bi * (2 * L_IN) + li;
    float cx[6], sx[6];
    #pragma unroll
    for (int ch = 0; ch < 2; ++ch)
        #pragma unroll
        for (int k = 0; k < 3; ++k)
            __sincosf(xb[ch * L_IN + k], &sx[ch * 3 + k], &cx[ch * 3 + k]);

    float acc[8];
    #pragma unroll
    for (int j = 0; j < 8; ++j) acc[j] = 0.f;

    const float* Tsrc = T + half * 8;
    switch (squad) {                         // uniform branch per wave
        case 0:  s_chunk< 0>(Tsrc, cx, sx, acc); break;
        case 1:  s_chunk<16>(Tsrc, cx, sx, acc); break;
        case 2:  s_chunk<32>(Tsrc, cx, sx, acc); break;
        default: s_chunk<48>(Tsrc, cx, sx, acc); break;
    }

    // ---- cross-squad reduction via LDS ----
    #pragma unroll
    for (int j = 0; j < 8; ++j)
        part[j][squad][half][cidx] = acc[j];   // addr = base+lane: free
    __syncthreads();

    // ---- reduce + coalesced store: 512 outputs/block, 128B runs ----
    #pragma unroll
    for (int i = 0; i < 2; ++i) {
        const int idx = tid + i * 256;         // [0,512)
        const int oc  = idx >> 5;              // [0,16)
        const int c32 = idx & 31;
        const int cs  = c0 + c32;
        const float v = part[oc & 7][0][oc >> 3][c32]
                      + part[oc & 7][1][oc >> 3][c32]
                      + part[oc & 7][2][oc >> 3][c32]
                      + part[oc & 7][3][oc >> 3][c32];
        if (cs < L_OUT)
            out[oc * NP + r0 * L_OUT + cs] = v;
    }
}

extern "C" void kernel_launch(void* const* d_in, const int* in_sizes, int n_in,
                              void* d_out, int out_size, void* d_ws, size_t ws_size,
                              hipStream_t stream) {
    const float* x = (const float*)d_in[0];   // (16, 2, 1024) fp32
    const float* w = (const float*)d_in[1];   // (16, 6, 2)    fp32
    float* out = (float*)d_out;               // (16, 16, 1022) fp32
    // grid = 16 r-slices x 32 c-chunks = 512 blocks -> 2 blocks/CU, 8 waves/CU
    qconv_kernel<<<dim3(512), dim3(256), 0, stream>>>(x, w, out);
}